// Round 5
// baseline (96.297 us; speedup 1.0000x reference)
//
#include <hip/hip_runtime.h>

#define MARGIN 0.3f

typedef __attribute__((ext_vector_type(8))) short short8;
typedef __attribute__((ext_vector_type(4))) float floatx4;

// ---- helpers ----------------------------------------------------------------

// order-preserving float->uint encoding so unsigned atomicMin == float min
__device__ __forceinline__ unsigned enc_f32(float f) {
    unsigned u = __float_as_uint(f);
    return (u & 0x80000000u) ? ~u : (u | 0x80000000u);
}
__device__ __forceinline__ float dec_f32(unsigned u) {
    return (u & 0x80000000u) ? __uint_as_float(u & 0x7fffffffu)
                             : __uint_as_float(~u);
}
// fp32 -> bf16 bits, round-to-nearest-even
__device__ __forceinline__ short f2bf(float f) {
    unsigned u = __float_as_uint(f);
    u = u + 0x7fffu + ((u >> 16) & 1u);
    return (short)(u >> 16);
}

// ---- kernel 0: tiny init (rowmin / cnt / out) --------------------------------
__global__ void init_kernel(unsigned* __restrict__ rowmin, unsigned* __restrict__ cnt,
                            float* __restrict__ out) {
    int i = blockIdx.x * 512 + threadIdx.x;
    rowmin[i] = 0xFFFFFFFFu;
    if (blockIdx.x == 0) {
        if (threadIdx.x < 32) cnt[threadIdx.x] = 0u;
        if (threadIdx.x == 0) out[0] = 0.0f;
    }
}

// ---- kernel 1: FUSED  stage(fp32->bf16) + MFMA GEMM + row-min + loss --------
// R5: single kernel, no intermediate workspace panels. grid 256 x 512 thr
// (8 waves), tile 512x512, 1 block/CU. XCD-bijective swizzle: XCD x owns
// row-groups {2x,2x+1} x all 16 col-groups -> a whole row-group lives on ONE
// XCD (rowmin/cnt atomics and sq-data all XCD-local).
// Staging (pre-barrier): A panel 512x128 fp32 -> bf16 register fragments
// (fully-coalesced 128B line reads); B panel 512x128 fp32 -> pre-scaled(-2)
// bf16 in LDS fragment-native layout via ds_write_b128 (contiguous per-thread
// reads); sq1/sq2 accumulated EXACTLY in fp32 alongside; posd for this
// block's 32-row slice. ONE __syncthreads, then a barrier-free, wait-free
// GEMM+min over the resident 128 KB panel. acc initialized to sq2[col] and B
// pre-scaled by -2 => MFMA emits sq2 - 2*dot directly; fold is fmin only.
__global__ __launch_bounds__(512, 2)
void fused_kernel(const float* __restrict__ z1, const float* __restrict__ z2,
                  float* __restrict__ posd,
                  unsigned* __restrict__ rowmin, unsigned* __restrict__ cnt,
                  float* __restrict__ out, int n)
{
    __shared__ __align__(16) short bt[65536];   // B panel: 512 cols x 128 k bf16
    __shared__ __align__(16) float s2l[512];    // sq2 for block's 512 cols (exact)
    __shared__ __align__(16) float sq1l[512];   // sq1 for block's 512 rows (exact)
    __shared__ float lsum[8];
    __shared__ int   fin_s;

    // bijective XCD swizzle (256 blocks = 8 xcd x 32, exact)
    const int bid = blockIdx.x;
    const int xcd = bid & 7, idx = bid >> 3;      // idx 0..31
    const int rg  = (xcd << 1) | (idx >> 4);      // row-group 0..15
    const int cgi = idx & 15;                     // col-group 0..15

    const int tid = threadIdx.x, w = tid >> 6, lane = tid & 63;
    const int quad = lane >> 4, l15 = lane & 15;
    const int rowbase = rg * 512 + w * 64;        // this wave's 64 rows
    const int colorig = cgi * 512;

    // ---- B stage: thread t owns col colorig+t (128 els, contiguous) --------
    {
        const float4* zb = (const float4*)(z2 + (size_t)(colorig + tid) * 128);
        float s2 = 0.f;
        #pragma unroll
        for (int kk = 0; kk < 4; ++kk) {
            float4 f[8];
            #pragma unroll
            for (int j = 0; j < 8; ++j) f[j] = zb[kk * 8 + j];
            #pragma unroll
            for (int j = 0; j < 8; ++j)
                s2 += f[j].x*f[j].x + f[j].y*f[j].y + f[j].z*f[j].z + f[j].w*f[j].w;
            #pragma unroll
            for (int q = 0; q < 4; ++q) {
                float4 a = f[q * 2], b = f[q * 2 + 1];
                short8 sc = { f2bf(-2.f*a.x), f2bf(-2.f*a.y), f2bf(-2.f*a.z), f2bf(-2.f*a.w),
                              f2bf(-2.f*b.x), f2bf(-2.f*b.y), f2bf(-2.f*b.z), f2bf(-2.f*b.w) };
                *(short8*)&bt[(tid >> 4) * 2048 + kk * 512 + q * 128 + (tid & 15) * 8] = sc;
            }
        }
        s2l[tid] = s2;
    }

    // ---- A stage: wave-local bf16 fragments + exact fp32 sq1 ---------------
    // fragment (sm,kk): lane(quad,l15) <- z1[rowbase+sm*16+l15][kk*32+quad*8..+7]
    // one (sm,kk) pair = 16 rows x full 128B line, perfectly coalesced.
    short8 af[4][4];
    {
        float s1p[4] = {0.f, 0.f, 0.f, 0.f};
        #pragma unroll
        for (int sm = 0; sm < 4; ++sm) {
            const float4* zr = (const float4*)(z1 + (size_t)(rowbase + sm * 16 + l15) * 128);
            #pragma unroll
            for (int kk = 0; kk < 4; ++kk) {
                float4 u0 = zr[kk * 8 + quad * 2];
                float4 u1 = zr[kk * 8 + quad * 2 + 1];
                s1p[sm] += u0.x*u0.x + u0.y*u0.y + u0.z*u0.z + u0.w*u0.w
                         + u1.x*u1.x + u1.y*u1.y + u1.z*u1.z + u1.w*u1.w;
                af[sm][kk] = { f2bf(u0.x), f2bf(u0.y), f2bf(u0.z), f2bf(u0.w),
                               f2bf(u1.x), f2bf(u1.y), f2bf(u1.z), f2bf(u1.w) };
            }
        }
        #pragma unroll
        for (int sm = 0; sm < 4; ++sm) {
            float s1 = s1p[sm];
            s1 += __shfl_xor(s1, 16);              // reduce across the 4 quads
            s1 += __shfl_xor(s1, 32);
            if (quad == 0) sq1l[w * 64 + sm * 16 + l15] = s1;
        }
    }

    // ---- posd stage: this block computes rows rg*512+cgi*32 .. +32 ---------
    {
        int ri = rg * 512 + cgi * 32 + (tid >> 4);
        int e  = (tid & 15) * 8;
        const float4* p1 = (const float4*)(z1 + (size_t)ri * 128 + e);
        const float4* p2 = (const float4*)(z2 + (size_t)ri * 128 + e);
        float4 a0 = p1[0], a1 = p1[1], b0 = p2[0], b1 = p2[1];
        float dx0 = a0.x-b0.x, dy0 = a0.y-b0.y, dz0 = a0.z-b0.z, dw0 = a0.w-b0.w;
        float dx1 = a1.x-b1.x, dy1 = a1.y-b1.y, dz1 = a1.z-b1.z, dw1 = a1.w-b1.w;
        float p2a = dx0*dx0 + dy0*dy0 + dz0*dz0 + dw0*dw0
                  + dx1*dx1 + dy1*dy1 + dz1*dz1 + dw1*dw1;
        #pragma unroll
        for (int m = 8; m >= 1; m >>= 1) p2a += __shfl_xor(p2a, m);
        if ((tid & 15) == 0) posd[ri] = sqrtf(p2a);
    }

    __syncthreads();    // panel + sq arrays resident; everything below is free-running

    float vmin[4][4];
    #pragma unroll
    for (int sm = 0; sm < 4; ++sm)
        #pragma unroll
        for (int reg = 0; reg < 4; ++reg)
            vmin[sm][reg] = 3.0e38f;

    #pragma unroll
    for (int S = 0; S < 8; ++S) {
        const short* bs_ = &bt[S * 8192];
        #pragma unroll
        for (int hf = 0; hf < 2; ++hf) {
            const int tcol = S * 64 + hf * 32;
            const int colbase = colorig + tcol;
            const float s2v0 = s2l[tcol + l15];
            const float s2v1 = s2l[tcol + 16 + l15];

            short8 bq[2][4];
            #pragma unroll
            for (int sn = 0; sn < 2; ++sn)
                #pragma unroll
                for (int kk = 0; kk < 4; ++kk)
                    bq[sn][kk] = *(const short8*)(bs_ + hf * 4096 + sn * 2048
                                                  + kk * 512 + lane * 8);

            floatx4 acc[4][2];
            #pragma unroll
            for (int sm = 0; sm < 4; ++sm)
                #pragma unroll
                for (int reg = 0; reg < 4; ++reg) {
                    acc[sm][0][reg] = s2v0;
                    acc[sm][1][reg] = s2v1;
                }

            __builtin_amdgcn_s_setprio(1);
            #pragma unroll
            for (int kk = 0; kk < 4; ++kk)
                #pragma unroll
                for (int sm = 0; sm < 4; ++sm)
                    #pragma unroll
                    for (int sn = 0; sn < 2; ++sn)
                        acc[sm][sn] = __builtin_amdgcn_mfma_f32_16x16x32_bf16(
                            af[sm][kk], bq[sn][kk], acc[sm][sn], 0, 0, 0);
            __builtin_amdgcn_s_setprio(0);

            if (colbase < rowbase + 64 && rowbase < colbase + 32) {
                #pragma unroll
                for (int sm = 0; sm < 4; ++sm)
                    #pragma unroll
                    for (int reg = 0; reg < 4; ++reg) {
                        int gi = rowbase + sm * 16 + quad * 4 + reg;
                        float v0 = acc[sm][0][reg];
                        float v1 = acc[sm][1][reg];
                        v0 = (gi == colbase + l15)      ? 3.0e38f : v0;
                        v1 = (gi == colbase + 16 + l15) ? 3.0e38f : v1;
                        vmin[sm][reg] = fminf(vmin[sm][reg], fminf(v0, v1));
                    }
            } else {
                #pragma unroll
                for (int sm = 0; sm < 4; ++sm)
                    #pragma unroll
                    for (int reg = 0; reg < 4; ++reg)
                        vmin[sm][reg] = fminf(vmin[sm][reg],
                            fminf(acc[sm][0][reg], acc[sm][1][reg]));
            }
        }
    }

    // min across each quad's 16 lanes, one atomicMin per row (XCD-local)
    #pragma unroll
    for (int sm = 0; sm < 4; ++sm)
        #pragma unroll
        for (int reg = 0; reg < 4; ++reg) {
            float vm = vmin[sm][reg];
            #pragma unroll
            for (int m = 8; m >= 1; m >>= 1)
                vm = fminf(vm, __shfl_xor(vm, m));
            if (l15 == 0)
                atomicMin(&rowmin[rowbase + sm * 16 + quad * 4 + reg], enc_f32(vm));
        }

    __syncthreads();
    if (tid == 0) {
        __threadfence();    // release: this block's mins + posd visible
        fin_s = (atomicAdd(&cnt[rg], 1u) == 15u);   // 16 col-blocks per rg
    }
    __syncthreads();
    if (!fin_s) return;
    __threadfence();        // acquire: see all 16 blocks' mins + posd

    // fused loss for rows [rg*512, rg*512+512): thread = one row.
    // sq1l is in LDS (this block staged the same A rows); posd from global.
    {
        int i = rg * 512 + tid;
        unsigned rm = atomicMin(&rowmin[i], 0xFFFFFFFFu);   // coherent forced read
        float hard = sqrtf(fmaxf(sq1l[tid] + dec_f32(rm), 0.0f));
        float l = fmaxf(posd[i] - hard + MARGIN, 0.0f);
        #pragma unroll
        for (int m = 32; m >= 1; m >>= 1) l += __shfl_xor(l, m);
        if (lane == 0) lsum[w] = l;
    }
    __syncthreads();
    if (tid == 0) {
        float t = 0.f;
        #pragma unroll
        for (int i = 0; i < 8; ++i) t += lsum[i];
        atomicAdd(out, t / (float)n);
    }
}

// ---- launch -----------------------------------------------------------------
extern "C" void kernel_launch(void* const* d_in, const int* in_sizes, int n_in,
                              void* d_out, int out_size, void* d_ws, size_t ws_size,
                              hipStream_t stream) {
    const float* z1 = (const float*)d_in[0];
    const float* z2 = (const float*)d_in[1];
    const int n = in_sizes[0] / 128;            // 8192

    char* ws = (char*)d_ws;
    float*    posd   = (float*)ws;                       // 32 KB
    unsigned* rowmin = (unsigned*)(ws + (size_t)n * 4);  // 32 KB
    unsigned* cnt    = (unsigned*)(ws + (size_t)n * 8);  // 128 B
    float*    out    = (float*)d_out;

    init_kernel<<<n / 512, 512, 0, stream>>>(rowmin, cnt, out);
    fused_kernel<<<(n / 512) * (n / 512), 512, 0, stream>>>(
        z1, z2, posd, rowmin, cnt, out, n);
}

// Round 6
// 86.445 us; speedup vs baseline: 1.1140x; 1.1140x over previous
//
#include <hip/hip_runtime.h>

#define MARGIN 0.3f

typedef __attribute__((ext_vector_type(8))) short short8;
typedef __attribute__((ext_vector_type(4))) float floatx4;

// ---- helpers ----------------------------------------------------------------

// order-preserving float->uint encoding so unsigned atomicMin == float min
__device__ __forceinline__ unsigned enc_f32(float f) {
    unsigned u = __float_as_uint(f);
    return (u & 0x80000000u) ? ~u : (u | 0x80000000u);
}
__device__ __forceinline__ float dec_f32(unsigned u) {
    return (u & 0x80000000u) ? __uint_as_float(u & 0x7fffffffu)
                             : __uint_as_float(~u);
}
// fp32 -> bf16 bits, round-to-nearest-even
__device__ __forceinline__ short f2bf(float f) {
    unsigned u = __float_as_uint(f);
    u = u + 0x7fffu + ((u >> 16) & 1u);
    return (short)(u >> 16);
}

// direct global->LDS DMA (no VGPR round-trip). LDS dest is wave-uniform
// base + lane*size — all call sites below respect that.
__device__ __forceinline__ void gload_lds16(const void* g, void* l) {
    __builtin_amdgcn_global_load_lds(
        (const __attribute__((address_space(1))) void*)g,
        (__attribute__((address_space(3))) void*)l, 16, 0, 0);
}
__device__ __forceinline__ void gload_lds4(const void* g, void* l) {
    __builtin_amdgcn_global_load_lds(
        (const __attribute__((address_space(1))) void*)g,
        (__attribute__((address_space(3))) void*)l, 4, 0, 0);
}

// Fragment-native global layout: element (row, k) with g16=row/16, r=row%16,
// kk=k/32, q=(k%32)/8, e=k%8 lives at  g16*2048 + kk*512 + q*128 + r*8 + e.
// A wave's fragment load for (g16, kk) is base + lane*8 shorts = 64 lanes x
// 16 B CONTIGUOUS — the global->LDS stage is a linear memcpy.

// ---- kernel 1: prepass (as R4) ----------------------------------------------
__global__ void prep_kernel(const float* __restrict__ z1, const float* __restrict__ z2,
                            short* __restrict__ z1b, short* __restrict__ z2b,
                            float* __restrict__ sq1, float* __restrict__ sq2,
                            float* __restrict__ posd, unsigned* __restrict__ rowmin,
                            unsigned* __restrict__ cnt, float* __restrict__ out) {
    int h = blockIdx.x * 256 + threadIdx.x;     // 0 .. n*16-1
    int row = h >> 4, p = h & 15;
    int kk = p >> 2, q = p & 3;
    int f0 = row * 32 + kk * 8 + q * 2;         // first float4 index
    float4 fa0 = ((const float4*)z1)[f0], fa1 = ((const float4*)z1)[f0 + 1];
    float4 fb0 = ((const float4*)z2)[f0], fb1 = ((const float4*)z2)[f0 + 1];
    short8 sa = { f2bf(fa0.x), f2bf(fa0.y), f2bf(fa0.z), f2bf(fa0.w),
                  f2bf(fa1.x), f2bf(fa1.y), f2bf(fa1.z), f2bf(fa1.w) };
    // B pre-scaled by -2 (exact): GEMM accumulates a * (-2b)
    short8 sb = { f2bf(-2.f*fb0.x), f2bf(-2.f*fb0.y), f2bf(-2.f*fb0.z), f2bf(-2.f*fb0.w),
                  f2bf(-2.f*fb1.x), f2bf(-2.f*fb1.y), f2bf(-2.f*fb1.z), f2bf(-2.f*fb1.w) };
    size_t off = (size_t)(row >> 4) * 2048 + kk * 512 + q * 128 + (row & 15) * 8;
    __builtin_nontemporal_store(sa, (short8*)&z1b[off]);
    __builtin_nontemporal_store(sb, (short8*)&z2b[off]);

    float s1 = fa0.x*fa0.x + fa0.y*fa0.y + fa0.z*fa0.z + fa0.w*fa0.w
             + fa1.x*fa1.x + fa1.y*fa1.y + fa1.z*fa1.z + fa1.w*fa1.w;
    float s2 = fb0.x*fb0.x + fb0.y*fb0.y + fb0.z*fb0.z + fb0.w*fb0.w
             + fb1.x*fb1.x + fb1.y*fb1.y + fb1.z*fb1.z + fb1.w*fb1.w;
    float dx0 = fa0.x-fb0.x, dy0 = fa0.y-fb0.y, dz0 = fa0.z-fb0.z, dw0 = fa0.w-fb0.w;
    float dx1 = fa1.x-fb1.x, dy1 = fa1.y-fb1.y, dz1 = fa1.z-fb1.z, dw1 = fa1.w-fb1.w;
    float p2 = dx0*dx0 + dy0*dy0 + dz0*dz0 + dw0*dw0
             + dx1*dx1 + dy1*dy1 + dz1*dz1 + dw1*dw1;
    #pragma unroll
    for (int m = 8; m >= 1; m >>= 1) {          // 16 threads per row
        s1 += __shfl_xor(s1, m);
        s2 += __shfl_xor(s2, m);
        p2 += __shfl_xor(p2, m);
    }
    if (p == 0) {
        __builtin_nontemporal_store(s1, &sq1[row]);
        __builtin_nontemporal_store(s2, &sq2[row]);
        __builtin_nontemporal_store(sqrtf(p2), &posd[row]);
    }

    if (threadIdx.x < 16)
        __builtin_nontemporal_store(0xFFFFFFFFu, &rowmin[blockIdx.x * 16 + threadIdx.x]);
    if (blockIdx.x == 0) {
        if (threadIdx.x < 32) cnt[threadIdx.x] = 0u;
        if (threadIdx.x == 0) out[0] = 0.0f;
    }
}

// ---- kernel 2: 512x512 tile, 16-WAVE blocks (concurrency A/B vs R4) ---------
// grid 256 x 1024 thr = 16 waves/CU (4/SIMD) — R4 ran 8 waves/CU (2/SIMD) at
// identical traffic/tiling. This isolates wave-level latency hiding, the one
// first-order variable never varied across R0-R5 (every structure landed at
// 35-55 us with all pipes <18%). Per-wave output halved to 32 rows x 512 cols
// (af[2][4], acc[2][2], ~110 VGPR <= 128 so 4 waves/SIMD fit).
// B panel (512 cols x 128 k = 128 KB) fully issued in prologue as 8 x 16 KB
// LDS buffers (1 DMA instr/thread each at 1024 thr); superphase S waits
// vmcnt(7-S) — later buffers stay in flight, latency paid once.
__global__ __launch_bounds__(1024, 1)
void gemm_min_kernel(const short* __restrict__ z1b, const short* __restrict__ z2b,
                     const float* __restrict__ sq1, const float* __restrict__ sq2,
                     const float* __restrict__ posd,
                     unsigned* __restrict__ rowmin, unsigned* __restrict__ cnt,
                     float* __restrict__ out, int n)
{
    __shared__ __align__(16) short sb[8][8192];   // 8 x (64 cols x 128 k) bf16
    __shared__ __align__(16) float s2l[512];      // sq2 slice for block's cols
    __shared__ float lsum[8];
    __shared__ int   fin_s;

    // bijective XCD swizzle (256 blocks = 8 xcd x 32, exact)
    const int bid = blockIdx.x;
    const int xcd = bid & 7, idx = bid >> 3;      // idx 0..31
    const int rg  = (xcd << 1) | (idx >> 4);      // row-group 0..15
    const int cgi = idx & 15;                     // col-group 0..15

    const int tid = threadIdx.x, w = tid >> 6, lane = tid & 63;
    const int quad = lane >> 4, l15 = lane & 15;
    const int rowbase = rg * 512 + w * 32;        // this wave's 32 rows
    const int colorig = cgi * 512;

    const short* gb = z2b + (size_t)(cgi * 32) * 2048;   // block's B panel

    // ---- prologue: issue EVERYTHING. per-wave vmem issue order (uniform):
    //   buf0 (1) | s2l (1) | af (8) | buf1..7 (1 each) = 17 outstanding.
    // sched_barrier(0) pins group order so counted vmcnt stays sound.
    gload_lds16(gb + tid * 8, &sb[0][tid * 8]);
    __builtin_amdgcn_sched_barrier(0);
    // s2l: wave w covers s2l[(w&7)*64 .. +64) (waves 8-15 duplicate 0-7 with
    // identical data — benign; keeps per-wave vmem counts uniform).
    gload_lds4(sq2 + colorig + (w & 7) * 64 + lane, &s2l[(w & 7) * 64]);
    __builtin_amdgcn_sched_barrier(0);

    // persistent A fragments: af[sm][kk] = A[m = l15 + sm*16 (+rowbase)][kk*32+quad*8 ..+7]
    short8 af[2][4];
    #pragma unroll
    for (int sm = 0; sm < 2; ++sm) {
        const short* pa = z1b + (size_t)(rg * 32 + w * 2 + sm) * 2048 + lane * 8;
        #pragma unroll
        for (int kk = 0; kk < 4; ++kk)
            af[sm][kk] = *(const short8*)(pa + kk * 512);
    }
    __builtin_amdgcn_sched_barrier(0);
    #pragma unroll
    for (int s = 1; s < 8; ++s) {
        gload_lds16(gb + (size_t)s * 8192 + tid * 8, &sb[s][tid * 8]);
        __builtin_amdgcn_sched_barrier(0);
    }

    float vmin[2][4];
    #pragma unroll
    for (int sm = 0; sm < 2; ++sm)
        #pragma unroll
        for (int reg = 0; reg < 4; ++reg)
            vmin[sm][reg] = 3.0e38f;

    // superphase S: wait own stage loads for buf S (counted — later bufs stay
    // in flight), barrier for cross-wave visibility, then pure LDS+MFMA+VALU.
#define SUPERPHASE(S, VMTXT)                                                   \
    do {                                                                       \
        asm volatile("s_waitcnt vmcnt(" VMTXT ")" ::: "memory");               \
        __builtin_amdgcn_sched_barrier(0);                                     \
        __builtin_amdgcn_s_barrier();                                          \
        __builtin_amdgcn_sched_barrier(0);                                     \
        const short* bs_ = &sb[S][0];                                          \
        _Pragma("unroll")                                                      \
        for (int hf = 0; hf < 2; ++hf) {                                       \
            const int tcol = (S) * 64 + hf * 32;                               \
            const int colbase = colorig + tcol;                                \
            const float s2v0 = s2l[tcol + l15];                                \
            const float s2v1 = s2l[tcol + 16 + l15];                           \
            short8 bq[2][4];                                                   \
            _Pragma("unroll")                                                  \
            for (int sn = 0; sn < 2; ++sn)                                     \
                _Pragma("unroll")                                              \
                for (int kk = 0; kk < 4; ++kk)                                 \
                    bq[sn][kk] = *(const short8*)(bs_ + hf * 4096 + sn * 2048  \
                                                  + kk * 512 + lane * 8);      \
            floatx4 acc[2][2];                                                 \
            _Pragma("unroll")                                                  \
            for (int sm = 0; sm < 2; ++sm) {                                   \
                _Pragma("unroll")                                              \
                for (int reg = 0; reg < 4; ++reg) {                            \
                    acc[sm][0][reg] = s2v0;                                    \
                    acc[sm][1][reg] = s2v1;                                    \
                }                                                              \
            }                                                                  \
            __builtin_amdgcn_s_setprio(1);                                     \
            _Pragma("unroll")                                                  \
            for (int kk = 0; kk < 4; ++kk)                                     \
                _Pragma("unroll")                                              \
                for (int sm = 0; sm < 2; ++sm)                                 \
                    _Pragma("unroll")                                          \
                    for (int sn = 0; sn < 2; ++sn)                             \
                        acc[sm][sn] = __builtin_amdgcn_mfma_f32_16x16x32_bf16( \
                            af[sm][kk], bq[sn][kk], acc[sm][sn], 0, 0, 0);     \
            __builtin_amdgcn_s_setprio(0);                                     \
            if (colbase < rowbase + 32 && rowbase < colbase + 32) {            \
                _Pragma("unroll")                                              \
                for (int sm = 0; sm < 2; ++sm)                                 \
                    _Pragma("unroll")                                          \
                    for (int reg = 0; reg < 4; ++reg) {                        \
                        int gi = rowbase + sm * 16 + quad * 4 + reg;           \
                        float v0 = acc[sm][0][reg];                            \
                        float v1 = acc[sm][1][reg];                            \
                        v0 = (gi == colbase + l15)      ? 3.0e38f : v0;        \
                        v1 = (gi == colbase + 16 + l15) ? 3.0e38f : v1;        \
                        vmin[sm][reg] = fminf(vmin[sm][reg], fminf(v0, v1));   \
                    }                                                          \
            } else {                                                           \
                _Pragma("unroll")                                              \
                for (int sm = 0; sm < 2; ++sm)                                 \
                    _Pragma("unroll")                                          \
                    for (int reg = 0; reg < 4; ++reg)                          \
                        vmin[sm][reg] = fminf(vmin[sm][reg],                   \
                            fminf(acc[sm][0][reg], acc[sm][1][reg]));          \
            }                                                                  \
        }                                                                      \
    } while (0)

    SUPERPHASE(0, "7");
    SUPERPHASE(1, "6");
    SUPERPHASE(2, "5");
    SUPERPHASE(3, "4");
    SUPERPHASE(4, "3");
    SUPERPHASE(5, "2");
    SUPERPHASE(6, "1");
    SUPERPHASE(7, "0");
#undef SUPERPHASE

    // min across each quad's 16 lanes, one atomicMin per row (XCD-local)
    #pragma unroll
    for (int sm = 0; sm < 2; ++sm)
        #pragma unroll
        for (int reg = 0; reg < 4; ++reg) {
            float vm = vmin[sm][reg];
            #pragma unroll
            for (int m = 8; m >= 1; m >>= 1)
                vm = fminf(vm, __shfl_xor(vm, m));
            if (l15 == 0)
                atomicMin(&rowmin[rowbase + sm * 16 + quad * 4 + reg], enc_f32(vm));
        }

    __syncthreads();
    if (tid == 0) {
        __threadfence();    // release: this block's mins visible before bump
        fin_s = (atomicAdd(&cnt[rg], 1u) == 15u);   // 16 col-blocks per rg
    }
    __syncthreads();
    if (!fin_s) return;
    __threadfence();        // acquire: see all 16 blocks' mins

    // fused loss for rows [rg*512, rg*512+512): threads 0..511 = one row each
    if (tid < 512) {
        int i = rg * 512 + tid;
        unsigned rm = atomicMin(&rowmin[i], 0xFFFFFFFFu);   // coherent forced read
        float hard = sqrtf(fmaxf(sq1[i] + dec_f32(rm), 0.0f));
        float l = fmaxf(posd[i] - hard + MARGIN, 0.0f);
        #pragma unroll
        for (int m = 32; m >= 1; m >>= 1) l += __shfl_xor(l, m);
        if (lane == 0) lsum[w] = l;
    }
    __syncthreads();
    if (tid == 0) {
        float t = 0.f;
        #pragma unroll
        for (int i = 0; i < 8; ++i) t += lsum[i];
        atomicAdd(out, t / (float)n);
    }
}

// ---- launch -----------------------------------------------------------------
extern "C" void kernel_launch(void* const* d_in, const int* in_sizes, int n_in,
                              void* d_out, int out_size, void* d_ws, size_t ws_size,
                              hipStream_t stream) {
    const float* z1 = (const float*)d_in[0];
    const float* z2 = (const float*)d_in[1];
    const int n = in_sizes[0] / 128;            // 8192

    char* ws = (char*)d_ws;
    short*    z1b    = (short*)ws;                                     // 2 MB
    short*    z2b    = (short*)(ws + (size_t)n * 128 * 2);             // 2 MB
    float*    sq1    = (float*)(ws + (size_t)n * 128 * 4);             // 32 KB
    float*    sq2    = (float*)(ws + (size_t)n * 128 * 4 + n * 4);     // 32 KB
    float*    posd   = (float*)(ws + (size_t)n * 128 * 4 + n * 8);     // 32 KB
    unsigned* rowmin = (unsigned*)(ws + (size_t)n * 128 * 4 + n * 12); // 32 KB
    unsigned* cnt    = (unsigned*)(ws + (size_t)n * 128 * 4 + n * 16); // 128 B
    float*    out    = (float*)d_out;

    prep_kernel<<<n / 16, 256, 0, stream>>>(z1, z2, z1b, z2b, sq1, sq2, posd,
                                            rowmin, cnt, out);
    gemm_min_kernel<<<(n / 512) * (n / 512), 1024, 0, stream>>>(
        z1b, z2b, sq1, sq2, posd, rowmin, cnt, out, n);
}